// Round 12
// baseline (69.078 us; speedup 1.0000x reference)
//
#include <hip/hip_runtime.h>
#include <hip/hip_bf16.h>

typedef __attribute__((ext_vector_type(4))) float f32x4;
typedef __attribute__((ext_vector_type(16))) float f32x16;
typedef __attribute__((ext_vector_type(4))) float f4;
typedef __attribute__((ext_vector_type(8))) short bf16x8;
typedef __attribute__((ext_vector_type(4))) short s16x4;
typedef __attribute__((ext_vector_type(4))) unsigned u32x4;

#define T_LEN 2048
#define SPAD 72
// log2(e)/64: folds BOTH 1/8 scale factors and the exp->exp2 conversion.
#define QSCALE 0.022542110013890054f

// LDS slot swizzle: mixes row bits 0-2 and 3-5 -> any lane group (stride
// 1/4/8) hits 8 distinct 16B slots. Verified: bank conflicts = 0 (round 11).
#define SWZ(r) (((r) ^ ((r) >> 3)) & 7)

__device__ inline short f2bf(float f) {
  unsigned u = __builtin_bit_cast(unsigned, f);
  return (short)((u + 0x7fffu + ((u >> 16) & 1u)) >> 16);
}

// ---------------------------------------------------------------------------
// prep_t: fp32 -> bf16 per-head transpose. sel=0: Q (linear [t][c]),
// PRE-SCALED by log2(e)/64. sel=1: K (tiled [stile][row][c ^ (SWZ(row)<<3)]).
// grid = 2048, block = 256.
// ---------------------------------------------------------------------------
__global__ __launch_bounds__(256) void prep_t(const float* __restrict__ qkv,
                                              short* __restrict__ qt,
                                              short* __restrict__ kt) {
  __shared__ float tile[64][65];
  const int bid = blockIdx.x;
  const int tch = bid & 31;
  const int head = (bid >> 5) & 31;
  const int sel = bid >> 10;
  const int b = head >> 3, h = head & 7;
  const float* src = qkv + ((size_t)b * 1536 + sel * 512 + h * 64) * T_LEN + tch * 64;
  short* dst = (sel ? kt : qt) + (size_t)head * T_LEN * 64 + (size_t)tch * 64 * 64;
  const int tid = threadIdx.x;
  const float sc = sel ? 1.0f : QSCALE;

  for (int e = tid; e < 4096; e += 256) {
    int c = e >> 6, t = e & 63;
    tile[c][t] = src[(size_t)c * T_LEN + t];
  }
  __syncthreads();
  for (int e = tid; e < 2048; e += 256) {
    int t = e >> 5, c2 = (e & 31) * 2;
    unsigned lo = (unsigned short)f2bf(tile[c2][t] * sc);
    unsigned hi = (unsigned short)f2bf(tile[c2 + 1][t] * sc);
    int cdst = sel ? (c2 ^ (SWZ(t) << 3)) : c2;
    *(unsigned*)&dst[t * 64 + cdst] = lo | (hi << 16);
  }
}

// ---------------------------------------------------------------------------
// prep_v: fp32 -> bf16 V, tiled per head [stile][c][s ^ (SWZ(c)<<3)].
// grid = 4096, block = 256.
// ---------------------------------------------------------------------------
__global__ __launch_bounds__(256) void prep_v(const float* __restrict__ qkv,
                                              short* __restrict__ v_out) {
  int id = blockIdx.x * 256 + threadIdx.x;
  int s4 = id & 15;
  int c = (id >> 4) & 63;
  int stile = (id >> 10) & 31;
  int head = id >> 15;
  int b = head >> 3, h = head & 7;
  const float* src =
      qkv + ((size_t)b * 1536 + 1024 + h * 64 + c) * T_LEN + stile * 64 + s4 * 4;
  f4 s = *(const f4*)src;
  s16x4 o;
#pragma unroll
  for (int j = 0; j < 4; ++j) o[j] = f2bf(s[j]);
  size_t dsts = (((size_t)head * 32 + stile) * 64 + c) * 64 + ((s4 * 4) ^ (SWZ(c) << 3));
  *(s16x4*)&v_out[dsts] = o;
}

// ---------------------------------------------------------------------------
// attn11: 64 q-rows per wave (two 32-col Q operand sets A/B). Each K/V
// fragment ds_read now feeds TWO MFMAs -> LDS read traffic per unit work
// halves (round-11 diagnosis: ds_read_b128 throughput was the binding pipe
// at ~1536 of ~1800 cyc/CU-iter). Both P-sets packed before PV so V is
// read once. grid = 256 = qblk(8) x head(32); block = 256 (4 waves x 64 q).
// ---------------------------------------------------------------------------
__global__ __launch_bounds__(256, 1) void attn11(const short* __restrict__ Qt,
                                                 const short* __restrict__ Kt,
                                                 const short* __restrict__ Vb,
                                                 float* __restrict__ out) {
  __shared__ short KV[2][2][4096];  // [buf][0=K,1=V][64x64 swizzled tile]

  const int bid = blockIdx.x;
  const int head = bid & 31;  // head pinned to one XCD's L2
  const int qblk = bid >> 5;  // 0..7

  const int tid = threadIdx.x;
  const int wave = tid >> 6;
  const int lane = tid & 63;
  const int l31 = lane & 31;
  const int hi = lane >> 5;

  const int t0 = qblk * 256 + wave * 64;  // rows t0..t0+63 (sets A,B)

  const short* Qh = Qt + (size_t)head * 131072;
  const short* Kh = Kt + (size_t)head * 131072;
  const short* Vh = Vb + (size_t)head * 131072;
  float* O = out + (size_t)head * 131072;

  const int sw0 = SWZ(l31) << 3;
  const int sw1 = SWZ(l31 + 32) << 3;

  auto stage = [&](int buf, int it) {
#pragma unroll
    for (int j = 0; j < 4; ++j) {
      const int chunk = wave * 4 + j;  // 0-7 = K, 8-15 = V
      const short* g = (chunk < 8 ? Kh : Vh) + it * 4096 + (chunk & 7) * 512 + lane * 8;
      short* l = &KV[buf][chunk >> 3][(chunk & 7) * 512];
      __builtin_amdgcn_global_load_lds((const __attribute__((address_space(1))) void*)g,
                                       (__attribute__((address_space(3))) void*)l,
                                       16, 0, 0);
    }
  };

  // Q (B operand) sets: lane holds B[k=c=ck*16+hi*8+j][col=t]
  bf16x8 aqA[4], aqB[4];
#pragma unroll
  for (int ck = 0; ck < 4; ++ck) {
    aqA[ck] = *(const bf16x8*)&Qh[(size_t)(t0 + l31) * 64 + ck * 16 + hi * 8];
    aqB[ck] = *(const bf16x8*)&Qh[(size_t)(t0 + 32 + l31) * 64 + ck * 16 + hi * 8];
  }

  float lA = 0.f, lB = 0.f;
  f32x16 oA0, oA1, oB0, oB1;
#pragma unroll
  for (int j = 0; j < 16; ++j) { oA0[j] = 0.f; oA1[j] = 0.f; oB0[j] = 0.f; oB1[j] = 0.f; }

  // p = exp2(s) -> psum -> packed PV B-fragments (cvt_pk + permlane32_swap)
  auto pack = [&](const f32x16& s0, const f32x16& s1, bf16x8(&pf)[4], float& l_acc) {
    float ps0 = 0.f, ps1 = 0.f, ps2 = 0.f, ps3 = 0.f;
    const f32x16* sv[2] = {&s0, &s1};
#pragma unroll
    for (int sbk = 0; sbk < 2; ++sbk) {
      float p[16];
#pragma unroll
      for (int j = 0; j < 16; ++j) p[j] = __builtin_amdgcn_exp2f((*sv[sbk])[j]);
      ps0 += p[0] + p[4] + p[8] + p[12];
      ps1 += p[1] + p[5] + p[9] + p[13];
      ps2 += p[2] + p[6] + p[10] + p[14];
      ps3 += p[3] + p[7] + p[11] + p[15];
      unsigned w0, w1, w2, w3, w4, w5, w6, w7;
      asm("v_cvt_pk_bf16_f32 %0, %1, %2" : "=v"(w0) : "v"(p[0]), "v"(p[1]));
      asm("v_cvt_pk_bf16_f32 %0, %1, %2" : "=v"(w1) : "v"(p[2]), "v"(p[3]));
      asm("v_cvt_pk_bf16_f32 %0, %1, %2" : "=v"(w2) : "v"(p[4]), "v"(p[5]));
      asm("v_cvt_pk_bf16_f32 %0, %1, %2" : "=v"(w3) : "v"(p[6]), "v"(p[7]));
      asm("v_cvt_pk_bf16_f32 %0, %1, %2" : "=v"(w4) : "v"(p[8]), "v"(p[9]));
      asm("v_cvt_pk_bf16_f32 %0, %1, %2" : "=v"(w5) : "v"(p[10]), "v"(p[11]));
      asm("v_cvt_pk_bf16_f32 %0, %1, %2" : "=v"(w6) : "v"(p[12]), "v"(p[13]));
      asm("v_cvt_pk_bf16_f32 %0, %1, %2" : "=v"(w7) : "v"(p[14]), "v"(p[15]));
      // vdst.high <-> vsrc.low; vdst = low-s word: one swap fills two words
      asm("v_permlane32_swap_b32 %0, %1" : "+v"(w0), "+v"(w2));
      asm("v_permlane32_swap_b32 %0, %1" : "+v"(w1), "+v"(w3));
      asm("v_permlane32_swap_b32 %0, %1" : "+v"(w4), "+v"(w6));
      asm("v_permlane32_swap_b32 %0, %1" : "+v"(w5), "+v"(w7));
      u32x4 fe = {w0, w1, w2, w3};
      u32x4 fo = {w4, w5, w6, w7};
      pf[sbk * 2] = __builtin_bit_cast(bf16x8, fe);
      pf[sbk * 2 + 1] = __builtin_bit_cast(bf16x8, fo);
    }
    l_acc += (ps0 + ps1) + (ps2 + ps3);
  };

  auto tile_body = [&](int buf) {
    // ---- S^T = K Q^T for both q-sets; each K read feeds 2 MFMAs ----
    f32x16 sA0, sA1, sB0, sB1;
#pragma unroll
    for (int j = 0; j < 16; ++j) { sA0[j] = 0.f; sA1[j] = 0.f; sB0[j] = 0.f; sB1[j] = 0.f; }
    __builtin_amdgcn_s_setprio(1);
#pragma unroll
    for (int ck = 0; ck < 4; ++ck) {
      const bf16x8 k0 = *(const bf16x8*)&KV[buf][0][l31 * 64 + ((ck * 16 + hi * 8) ^ sw0)];
      const bf16x8 k1 = *(const bf16x8*)&KV[buf][0][(32 + l31) * 64 + ((ck * 16 + hi * 8) ^ sw1)];
      sA0 = __builtin_amdgcn_mfma_f32_32x32x16_bf16(k0, aqA[ck], sA0, 0, 0, 0);
      sA1 = __builtin_amdgcn_mfma_f32_32x32x16_bf16(k1, aqA[ck], sA1, 0, 0, 0);
      sB0 = __builtin_amdgcn_mfma_f32_32x32x16_bf16(k0, aqB[ck], sB0, 0, 0, 0);
      sB1 = __builtin_amdgcn_mfma_f32_32x32x16_bf16(k1, aqB[ck], sB1, 0, 0, 0);
    }
    __builtin_amdgcn_s_setprio(0);

    // ---- softmax + pack both sets (so V below is read once) ----
    bf16x8 pfA[4], pfB[4];
    pack(sA0, sA1, pfA, lA);
    pack(sB0, sB1, pfB, lB);

    // ---- O^T += V P^T; each V read feeds 2 MFMAs ----
    __builtin_amdgcn_s_setprio(1);
#pragma unroll
    for (int sc = 0; sc < 4; ++sc) {
      const bf16x8 v0 = *(const bf16x8*)&KV[buf][1][l31 * 64 + ((sc * 16 + hi * 8) ^ sw0)];
      const bf16x8 v1 = *(const bf16x8*)&KV[buf][1][(32 + l31) * 64 + ((sc * 16 + hi * 8) ^ sw1)];
      oA0 = __builtin_amdgcn_mfma_f32_32x32x16_bf16(v0, pfA[sc], oA0, 0, 0, 0);
      oA1 = __builtin_amdgcn_mfma_f32_32x32x16_bf16(v1, pfA[sc], oA1, 0, 0, 0);
      oB0 = __builtin_amdgcn_mfma_f32_32x32x16_bf16(v0, pfB[sc], oB0, 0, 0, 0);
      oB1 = __builtin_amdgcn_mfma_f32_32x32x16_bf16(v1, pfB[sc], oB1, 0, 0, 0);
    }
    __builtin_amdgcn_s_setprio(0);
  };

  stage(0, 0);
  __syncthreads();

  for (int itp = 0; itp < 16; ++itp) {
    const int it = itp * 2;
    stage(1, it + 1);                 // prefetch into buf1 under compute(buf0)
    tile_body(0);
    __syncthreads();                  // prefetch landed; buf0 reusable
    if (it + 2 < 32) stage(0, it + 2);
    tile_body(1);
    __syncthreads();
  }

  // ---- epilogue: combine lane halves' l, write O[c][t] directly ----
  const float lAt = lA + __shfl_xor(lA, 32, 64);
  const float lBt = lB + __shfl_xor(lB, 32, 64);
  const float rlA = 1.0f / lAt;
  const float rlB = 1.0f / lBt;
#pragma unroll
  for (int j = 0; j < 16; ++j) {
    const int c0 = (j & 3) + 8 * (j >> 2) + 4 * hi;
    O[(size_t)c0 * T_LEN + t0 + l31] = oA0[j] * rlA;
    O[(size_t)(32 + c0) * T_LEN + t0 + l31] = oA1[j] * rlA;
    O[(size_t)c0 * T_LEN + t0 + 32 + l31] = oB0[j] * rlB;
    O[(size_t)(32 + c0) * T_LEN + t0 + 32 + l31] = oB1[j] * rlB;
  }
}

// ---------------------------------------------------------------------------
// Fallback (round-1 kernel) if ws_size is too small for the bf16 prep buffers.
// ---------------------------------------------------------------------------
__global__ __launch_bounds__(256) void attn_fwd(const float* __restrict__ qkv,
                                                float* __restrict__ out) {
  __shared__ short KtS[64][SPAD];
  __shared__ short VtS[64][SPAD];
  __shared__ short PbS[4][16][SPAD];

  const int bid = blockIdx.x;
  const int qt = bid & 31;
  const int head = bid >> 5;
  const int b = head >> 3, h = head & 7;

  const size_t base = ((size_t)b * 1536 + h * 64) * T_LEN;
  const float* Q = qkv + base;
  const float* K = qkv + base + (size_t)512 * T_LEN;
  const float* V = qkv + base + (size_t)1024 * T_LEN;
  float* O = out + ((size_t)b * 512 + h * 64) * T_LEN;

  const int tid = threadIdx.x;
  const int wave = tid >> 6;
  const int lane = tid & 63;
  const int l15 = lane & 15;
  const int l4 = lane >> 4;
  const int t0 = qt * 64 + wave * 16;

  bf16x8 aq[2];
#pragma unroll
  for (int kk = 0; kk < 2; ++kk)
#pragma unroll
    for (int j = 0; j < 8; ++j) {
      int c = kk * 32 + l4 * 8 + j;
      aq[kk][j] = f2bf(Q[(size_t)c * T_LEN + t0 + l15]);
    }

  float m_run[4], l_run[4];
  f32x4 o_acc[4];
#pragma unroll
  for (int r = 0; r < 4; ++r) { m_run[r] = -1e30f; l_run[r] = 0.f; }
#pragma unroll
  for (int n = 0; n < 4; ++n) o_acc[n] = (f32x4){0.f, 0.f, 0.f, 0.f};

  const float inv64 = 0.015625f;

  for (int s0 = 0; s0 < T_LEN; s0 += 64) {
    __syncthreads();
    for (int e = tid; e < 4096; e += 256) {
      int c = e >> 6, s = e & 63;
      KtS[s][c] = f2bf(K[(size_t)c * T_LEN + s0 + s]);
      VtS[c][s] = f2bf(V[(size_t)c * T_LEN + s0 + s]);
    }
    __syncthreads();

    f32x4 sacc[4];
#pragma unroll
    for (int n = 0; n < 4; ++n) {
      const bf16x8 bk0 = *(const bf16x8*)&KtS[16 * n + l15][l4 * 8];
      const bf16x8 bk1 = *(const bf16x8*)&KtS[16 * n + l15][32 + l4 * 8];
      f32x4 z = (f32x4){0.f, 0.f, 0.f, 0.f};
      z = __builtin_amdgcn_mfma_f32_16x16x32_bf16(aq[0], bk0, z, 0, 0, 0);
      z = __builtin_amdgcn_mfma_f32_16x16x32_bf16(aq[1], bk1, z, 0, 0, 0);
      sacc[n] = z;
    }

#pragma unroll
    for (int r = 0; r < 4; ++r) {
      float mx = fmaxf(fmaxf(sacc[0][r], sacc[1][r]),
                       fmaxf(sacc[2][r], sacc[3][r])) * inv64;
#pragma unroll
      for (int off = 8; off >= 1; off >>= 1)
        mx = fmaxf(mx, __shfl_xor(mx, off, 64));
      const float m_new = fmaxf(m_run[r], mx);
      const float alpha = __expf(m_run[r] - m_new);
      float psum = 0.f;
#pragma unroll
      for (int n = 0; n < 4; ++n) {
        float p = __expf(sacc[n][r] * inv64 - m_new);
        psum += p;
        PbS[wave][l4 * 4 + r][16 * n + l15] = f2bf(p);
      }
#pragma unroll
      for (int off = 8; off >= 1; off >>= 1)
        psum += __shfl_xor(psum, off, 64);
      l_run[r] = l_run[r] * alpha + psum;
      m_run[r] = m_new;
#pragma unroll
      for (int n = 0; n < 4; ++n) o_acc[n][r] *= alpha;
    }

    const bf16x8 ap0 = *(const bf16x8*)&PbS[wave][l15][l4 * 8];
    const bf16x8 ap1 = *(const bf16x8*)&PbS[wave][l15][32 + l4 * 8];
#pragma unroll
    for (int n = 0; n < 4; ++n) {
      const bf16x8 bv0 = *(const bf16x8*)&VtS[16 * n + l15][l4 * 8];
      const bf16x8 bv1 = *(const bf16x8*)&VtS[16 * n + l15][32 + l4 * 8];
      o_acc[n] = __builtin_amdgcn_mfma_f32_16x16x32_bf16(ap0, bv0, o_acc[n], 0, 0, 0);
      o_acc[n] = __builtin_amdgcn_mfma_f32_16x16x32_bf16(ap1, bv1, o_acc[n], 0, 0, 0);
    }
  }

#pragma unroll
  for (int n = 0; n < 4; ++n)
#pragma unroll
    for (int r = 0; r < 4; ++r) {
      const int c = 16 * n + l15;
      const int t = t0 + l4 * 4 + r;
      O[(size_t)c * T_LEN + t] = o_acc[n][r] / l_run[r];
    }
}

extern "C" void kernel_launch(void* const* d_in, const int* in_sizes, int n_in,
                              void* d_out, int out_size, void* d_ws, size_t ws_size,
                              hipStream_t stream) {
  const float* qkv = (const float*)d_in[0];
  float* out = (float*)d_out;
  const size_t per_buf = (size_t)32 * T_LEN * 64;
  const size_t need = per_buf * 3 * sizeof(short);
  if (ws_size >= need) {
    short* qt = (short*)d_ws;
    short* kt = qt + per_buf;
    short* vb = kt + per_buf;
    hipLaunchKernelGGL(prep_t, dim3(2048), dim3(256), 0, stream, qkv, qt, kt);
    hipLaunchKernelGGL(prep_v, dim3(4096), dim3(256), 0, stream, qkv, vb);
    hipLaunchKernelGGL(attn11, dim3(256), dim3(256), 0, stream, qt, kt, vb, out);
  } else {
    hipLaunchKernelGGL(attn_fwd, dim3(1024), dim3(256), 0, stream, qkv, out);
  }
}

// Round 13
// 58.397 us; speedup vs baseline: 1.1829x; 1.1829x over previous
//
#include <hip/hip_runtime.h>
#include <hip/hip_bf16.h>

typedef __attribute__((ext_vector_type(4))) float f32x4;
typedef __attribute__((ext_vector_type(16))) float f32x16;
typedef __attribute__((ext_vector_type(4))) float f4;
typedef __attribute__((ext_vector_type(8))) short bf16x8;
typedef __attribute__((ext_vector_type(4))) short s16x4;
typedef __attribute__((ext_vector_type(4))) unsigned u32x4;

#define T_LEN 2048
#define SPAD 72
// log2(e)/64: folds BOTH 1/8 scale factors and the exp->exp2 conversion.
#define QSCALE 0.022542110013890054f

// LDS slot swizzle: mixes row bits 0-2 and 3-5 -> any lane group (stride
// 1/4/8) hits 8 distinct 16B slots. Verified: bank conflicts = 0 (round 11).
#define SWZ(r) (((r) ^ ((r) >> 3)) & 7)

__device__ inline short f2bf(float f) {
  unsigned u = __builtin_bit_cast(unsigned, f);
  return (short)((u + 0x7fffu + ((u >> 16) & 1u)) >> 16);
}

// ---------------------------------------------------------------------------
// prep_t: fp32 -> bf16 per-head transpose. sel=0: Q (linear [t][c]),
// PRE-SCALED by log2(e)/64. sel=1: K (tiled [stile][row][c ^ (SWZ(row)<<3)]).
// grid = 2048, block = 256.
// ---------------------------------------------------------------------------
__global__ __launch_bounds__(256) void prep_t(const float* __restrict__ qkv,
                                              short* __restrict__ qt,
                                              short* __restrict__ kt) {
  __shared__ float tile[64][65];
  const int bid = blockIdx.x;
  const int tch = bid & 31;
  const int head = (bid >> 5) & 31;
  const int sel = bid >> 10;
  const int b = head >> 3, h = head & 7;
  const float* src = qkv + ((size_t)b * 1536 + sel * 512 + h * 64) * T_LEN + tch * 64;
  short* dst = (sel ? kt : qt) + (size_t)head * T_LEN * 64 + (size_t)tch * 64 * 64;
  const int tid = threadIdx.x;
  const float sc = sel ? 1.0f : QSCALE;

  for (int e = tid; e < 4096; e += 256) {
    int c = e >> 6, t = e & 63;
    tile[c][t] = src[(size_t)c * T_LEN + t];
  }
  __syncthreads();
  for (int e = tid; e < 2048; e += 256) {
    int t = e >> 5, c2 = (e & 31) * 2;
    unsigned lo = (unsigned short)f2bf(tile[c2][t] * sc);
    unsigned hi = (unsigned short)f2bf(tile[c2 + 1][t] * sc);
    int cdst = sel ? (c2 ^ (SWZ(t) << 3)) : c2;
    *(unsigned*)&dst[t * 64 + cdst] = lo | (hi << 16);
  }
}

// ---------------------------------------------------------------------------
// prep_v: fp32 -> bf16 V, tiled per head [stile][c][s ^ (SWZ(c)<<3)].
// grid = 4096, block = 256.
// ---------------------------------------------------------------------------
__global__ __launch_bounds__(256) void prep_v(const float* __restrict__ qkv,
                                              short* __restrict__ v_out) {
  int id = blockIdx.x * 256 + threadIdx.x;
  int s4 = id & 15;
  int c = (id >> 4) & 63;
  int stile = (id >> 10) & 31;
  int head = id >> 15;
  int b = head >> 3, h = head & 7;
  const float* src =
      qkv + ((size_t)b * 1536 + 1024 + h * 64 + c) * T_LEN + stile * 64 + s4 * 4;
  f4 s = *(const f4*)src;
  s16x4 o;
#pragma unroll
  for (int j = 0; j < 4; ++j) o[j] = f2bf(s[j]);
  size_t dsts = (((size_t)head * 32 + stile) * 64 + c) * 64 + ((s4 * 4) ^ (SWZ(c) << 3));
  *(s16x4*)&v_out[dsts] = o;
}

// ---------------------------------------------------------------------------
// attn13: round-12 diagnosis = serialization-bound at 2 waves/SIMD (pipe
// times SUM: LDS 43% + VALU 33% + MFMA 27% ~= 100% of wall). Fix: s-split
// WITHIN the block. 512 threads = 8 waves: waves 0-3 do s-tiles 0..15,
// waves 4-7 do s-tiles 16..31, same 128 q-rows (32/wave, attn10's proven
// shape). Grid 512 -> 2 blocks/CU -> 4 waves/SIMD issue diversity.
// No-max softmax makes the split combine purely additive: group 1 drops
// unnormalized O + partial l in LDS, group 0 adds & normalizes.
// grid = 512 = qblk(16) x head(32); block = 512.
// ---------------------------------------------------------------------------
__global__ __launch_bounds__(512, 4) void attn13(const short* __restrict__ Qt,
                                                 const short* __restrict__ Kt,
                                                 const short* __restrict__ Vb,
                                                 float* __restrict__ out) {
  __shared__ short KV[2][2][2][4096];  // [grp][buf][0=K,1=V][64x64 tile]

  const int bid = blockIdx.x;
  const int head = bid & 31;  // head pinned to one XCD's L2
  const int qblk = bid >> 5;  // 0..15

  const int tid = threadIdx.x;
  const int wave = tid >> 6;   // 0..7
  const int grp = wave >> 2;   // s-half
  const int wv = wave & 3;     // wave within group
  const int lane = tid & 63;
  const int l31 = lane & 31;
  const int hi = lane >> 5;

  const int t0 = qblk * 128 + wv * 32;  // this wave's 32 query rows
  const int sbase = grp * 16;           // this group's first s-tile

  const short* Qh = Qt + (size_t)head * 131072;
  const short* Kh = Kt + (size_t)head * 131072;
  const short* Vh = Vb + (size_t)head * 131072;
  float* O = out + (size_t)head * 131072;

  const int sw0 = SWZ(l31) << 3;
  const int sw1 = SWZ(l31 + 32) << 3;

  auto stage = [&](int buf, int it) {  // it = tile within group (0..15)
#pragma unroll
    for (int j = 0; j < 4; ++j) {
      const int chunk = wv * 4 + j;  // 0-7 = K, 8-15 = V
      const short* g =
          (chunk < 8 ? Kh : Vh) + (sbase + it) * 4096 + (chunk & 7) * 512 + lane * 8;
      short* l = &KV[grp][buf][chunk >> 3][(chunk & 7) * 512];
      __builtin_amdgcn_global_load_lds((const __attribute__((address_space(1))) void*)g,
                                       (__attribute__((address_space(3))) void*)l,
                                       16, 0, 0);
    }
  };

  // Q (B operand): lane holds B[k=c=ck*16+hi*8+j][col=t=l31]
  bf16x8 aq[4];
#pragma unroll
  for (int ck = 0; ck < 4; ++ck)
    aq[ck] = *(const bf16x8*)&Qh[(size_t)(t0 + l31) * 64 + ck * 16 + hi * 8];

  float l_lane = 0.f;
  f32x16 o_acc[2];
#pragma unroll
  for (int j = 0; j < 16; ++j) { o_acc[0][j] = 0.f; o_acc[1][j] = 0.f; }

  auto tile_body = [&](int buf) {
    f32x16 s0, s1;
#pragma unroll
    for (int j = 0; j < 16; ++j) { s0[j] = 0.f; s1[j] = 0.f; }
    __builtin_amdgcn_s_setprio(1);
#pragma unroll
    for (int ck = 0; ck < 4; ++ck) {
      const bf16x8 k0 = *(const bf16x8*)&KV[grp][buf][0][l31 * 64 + ((ck * 16 + hi * 8) ^ sw0)];
      s0 = __builtin_amdgcn_mfma_f32_32x32x16_bf16(k0, aq[ck], s0, 0, 0, 0);
      const bf16x8 k1 = *(const bf16x8*)&KV[grp][buf][0][(32 + l31) * 64 + ((ck * 16 + hi * 8) ^ sw1)];
      s1 = __builtin_amdgcn_mfma_f32_32x32x16_bf16(k1, aq[ck], s1, 0, 0, 0);
    }
    __builtin_amdgcn_s_setprio(0);

    float ps0 = 0.f, ps1 = 0.f, ps2 = 0.f, ps3 = 0.f;
    bf16x8 pf[4];
    const f32x16* sv[2] = {&s0, &s1};
#pragma unroll
    for (int sbk = 0; sbk < 2; ++sbk) {
      float p[16];
#pragma unroll
      for (int j = 0; j < 16; ++j) p[j] = __builtin_amdgcn_exp2f((*sv[sbk])[j]);
      ps0 += p[0] + p[4] + p[8] + p[12];
      ps1 += p[1] + p[5] + p[9] + p[13];
      ps2 += p[2] + p[6] + p[10] + p[14];
      ps3 += p[3] + p[7] + p[11] + p[15];
      unsigned w0, w1, w2, w3, w4, w5, w6, w7;
      asm("v_cvt_pk_bf16_f32 %0, %1, %2" : "=v"(w0) : "v"(p[0]), "v"(p[1]));
      asm("v_cvt_pk_bf16_f32 %0, %1, %2" : "=v"(w1) : "v"(p[2]), "v"(p[3]));
      asm("v_cvt_pk_bf16_f32 %0, %1, %2" : "=v"(w2) : "v"(p[4]), "v"(p[5]));
      asm("v_cvt_pk_bf16_f32 %0, %1, %2" : "=v"(w3) : "v"(p[6]), "v"(p[7]));
      asm("v_cvt_pk_bf16_f32 %0, %1, %2" : "=v"(w4) : "v"(p[8]), "v"(p[9]));
      asm("v_cvt_pk_bf16_f32 %0, %1, %2" : "=v"(w5) : "v"(p[10]), "v"(p[11]));
      asm("v_cvt_pk_bf16_f32 %0, %1, %2" : "=v"(w6) : "v"(p[12]), "v"(p[13]));
      asm("v_cvt_pk_bf16_f32 %0, %1, %2" : "=v"(w7) : "v"(p[14]), "v"(p[15]));
      // vdst.high <-> vsrc.low; vdst = low-s word: one swap fills two words
      asm("v_permlane32_swap_b32 %0, %1" : "+v"(w0), "+v"(w2));
      asm("v_permlane32_swap_b32 %0, %1" : "+v"(w1), "+v"(w3));
      asm("v_permlane32_swap_b32 %0, %1" : "+v"(w4), "+v"(w6));
      asm("v_permlane32_swap_b32 %0, %1" : "+v"(w5), "+v"(w7));
      u32x4 fe = {w0, w1, w2, w3};
      u32x4 fo = {w4, w5, w6, w7};
      pf[sbk * 2] = __builtin_bit_cast(bf16x8, fe);
      pf[sbk * 2 + 1] = __builtin_bit_cast(bf16x8, fo);
    }
    l_lane += (ps0 + ps1) + (ps2 + ps3);

    __builtin_amdgcn_s_setprio(1);
#pragma unroll
    for (int sc = 0; sc < 4; ++sc) {
      const bf16x8 v0 = *(const bf16x8*)&KV[grp][buf][1][l31 * 64 + ((sc * 16 + hi * 8) ^ sw0)];
      o_acc[0] = __builtin_amdgcn_mfma_f32_32x32x16_bf16(v0, pf[sc], o_acc[0], 0, 0, 0);
      const bf16x8 v1 = *(const bf16x8*)&KV[grp][buf][1][(32 + l31) * 64 + ((sc * 16 + hi * 8) ^ sw1)];
      o_acc[1] = __builtin_amdgcn_mfma_f32_32x32x16_bf16(v1, pf[sc], o_acc[1], 0, 0, 0);
    }
    __builtin_amdgcn_s_setprio(0);
  };

  stage(0, 0);
  __syncthreads();

  // 16 tiles per group, unroll-by-2 (buf compile-time constant)
  for (int itp = 0; itp < 8; ++itp) {
    const int it = itp * 2;
    stage(1, it + 1);                  // prefetch under compute(buf0)
    tile_body(0);
    __syncthreads();
    if (itp < 7) stage(0, it + 2);
    tile_body(1);
    __syncthreads();
  }

  // ---- combine: group-local l per row, then cross-group add via LDS ----
  const float lg = l_lane + __shfl_xor(l_lane, 32, 64);
  float* xb = (float*)&KV[0][0][0][0];  // 64 KB scratch; stride 33 -> no conflicts
  if (grp == 1) {
    float* dst = xb + (wv * 64 + lane) * 33;
#pragma unroll
    for (int j = 0; j < 16; ++j) { dst[j] = o_acc[0][j]; dst[16 + j] = o_acc[1][j]; }
    dst[32] = lg;
  }
  __syncthreads();
  if (grp == 0) {
    const float* src = xb + (wv * 64 + lane) * 33;
    const float rl = 1.0f / (lg + src[32]);
#pragma unroll
    for (int j = 0; j < 16; ++j) {
      const int c0 = (j & 3) + 8 * (j >> 2) + 4 * hi;
      O[(size_t)c0 * T_LEN + t0 + l31] = (o_acc[0][j] + src[j]) * rl;
      O[(size_t)(32 + c0) * T_LEN + t0 + l31] = (o_acc[1][j] + src[16 + j]) * rl;
    }
  }
}

// ---------------------------------------------------------------------------
// Fallback (round-1 kernel) if ws_size is too small for the bf16 prep buffers.
// ---------------------------------------------------------------------------
__global__ __launch_bounds__(256) void attn_fwd(const float* __restrict__ qkv,
                                                float* __restrict__ out) {
  __shared__ short KtS[64][SPAD];
  __shared__ short VtS[64][SPAD];
  __shared__ short PbS[4][16][SPAD];

  const int bid = blockIdx.x;
  const int qt = bid & 31;
  const int head = bid >> 5;
  const int b = head >> 3, h = head & 7;

  const size_t base = ((size_t)b * 1536 + h * 64) * T_LEN;
  const float* Q = qkv + base;
  const float* K = qkv + base + (size_t)512 * T_LEN;
  const float* V = qkv + base + (size_t)1024 * T_LEN;
  float* O = out + ((size_t)b * 512 + h * 64) * T_LEN;

  const int tid = threadIdx.x;
  const int wave = tid >> 6;
  const int lane = tid & 63;
  const int l15 = lane & 15;
  const int l4 = lane >> 4;
  const int t0 = qt * 64 + wave * 16;

  bf16x8 aq[2];
#pragma unroll
  for (int kk = 0; kk < 2; ++kk)
#pragma unroll
    for (int j = 0; j < 8; ++j) {
      int c = kk * 32 + l4 * 8 + j;
      aq[kk][j] = f2bf(Q[(size_t)c * T_LEN + t0 + l15]);
    }

  float m_run[4], l_run[4];
  f32x4 o_acc[4];
#pragma unroll
  for (int r = 0; r < 4; ++r) { m_run[r] = -1e30f; l_run[r] = 0.f; }
#pragma unroll
  for (int n = 0; n < 4; ++n) o_acc[n] = (f32x4){0.f, 0.f, 0.f, 0.f};

  const float inv64 = 0.015625f;

  for (int s0 = 0; s0 < T_LEN; s0 += 64) {
    __syncthreads();
    for (int e = tid; e < 4096; e += 256) {
      int c = e >> 6, s = e & 63;
      KtS[s][c] = f2bf(K[(size_t)c * T_LEN + s0 + s]);
      VtS[c][s] = f2bf(V[(size_t)c * T_LEN + s0 + s]);
    }
    __syncthreads();

    f32x4 sacc[4];
#pragma unroll
    for (int n = 0; n < 4; ++n) {
      const bf16x8 bk0 = *(const bf16x8*)&KtS[16 * n + l15][l4 * 8];
      const bf16x8 bk1 = *(const bf16x8*)&KtS[16 * n + l15][32 + l4 * 8];
      f32x4 z = (f32x4){0.f, 0.f, 0.f, 0.f};
      z = __builtin_amdgcn_mfma_f32_16x16x32_bf16(aq[0], bk0, z, 0, 0, 0);
      z = __builtin_amdgcn_mfma_f32_16x16x32_bf16(aq[1], bk1, z, 0, 0, 0);
      sacc[n] = z;
    }

#pragma unroll
    for (int r = 0; r < 4; ++r) {
      float mx = fmaxf(fmaxf(sacc[0][r], sacc[1][r]),
                       fmaxf(sacc[2][r], sacc[3][r])) * inv64;
#pragma unroll
      for (int off = 8; off >= 1; off >>= 1)
        mx = fmaxf(mx, __shfl_xor(mx, off, 64));
      const float m_new = fmaxf(m_run[r], mx);
      const float alpha = __expf(m_run[r] - m_new);
      float psum = 0.f;
#pragma unroll
      for (int n = 0; n < 4; ++n) {
        float p = __expf(sacc[n][r] * inv64 - m_new);
        psum += p;
        PbS[wave][l4 * 4 + r][16 * n + l15] = f2bf(p);
      }
#pragma unroll
      for (int off = 8; off >= 1; off >>= 1)
        psum += __shfl_xor(psum, off, 64);
      l_run[r] = l_run[r] * alpha + psum;
      m_run[r] = m_new;
#pragma unroll
      for (int n = 0; n < 4; ++n) o_acc[n][r] *= alpha;
    }

    const bf16x8 ap0 = *(const bf16x8*)&PbS[wave][l15][l4 * 8];
    const bf16x8 ap1 = *(const bf16x8*)&PbS[wave][l15][32 + l4 * 8];
#pragma unroll
    for (int n = 0; n < 4; ++n) {
      const bf16x8 bv0 = *(const bf16x8*)&VtS[16 * n + l15][l4 * 8];
      const bf16x8 bv1 = *(const bf16x8*)&VtS[16 * n + l15][32 + l4 * 8];
      o_acc[n] = __builtin_amdgcn_mfma_f32_16x16x32_bf16(ap0, bv0, o_acc[n], 0, 0, 0);
      o_acc[n] = __builtin_amdgcn_mfma_f32_16x16x32_bf16(ap1, bv1, o_acc[n], 0, 0, 0);
    }
  }

#pragma unroll
  for (int n = 0; n < 4; ++n)
#pragma unroll
    for (int r = 0; r < 4; ++r) {
      const int c = 16 * n + l15;
      const int t = t0 + l4 * 4 + r;
      O[(size_t)c * T_LEN + t] = o_acc[n][r] / l_run[r];
    }
}

extern "C" void kernel_launch(void* const* d_in, const int* in_sizes, int n_in,
                              void* d_out, int out_size, void* d_ws, size_t ws_size,
                              hipStream_t stream) {
  const float* qkv = (const float*)d_in[0];
  float* out = (float*)d_out;
  const size_t per_buf = (size_t)32 * T_LEN * 64;
  const size_t need = per_buf * 3 * sizeof(short);
  if (ws_size >= need) {
    short* qt = (short*)d_ws;
    short* kt = qt + per_buf;
    short* vb = kt + per_buf;
    hipLaunchKernelGGL(prep_t, dim3(2048), dim3(256), 0, stream, qkv, qt, kt);
    hipLaunchKernelGGL(prep_v, dim3(4096), dim3(256), 0, stream, qkv, vb);
    hipLaunchKernelGGL(attn13, dim3(512), dim3(512), 0, stream, qt, kt, vb, out);
  } else {
    hipLaunchKernelGGL(attn_fwd, dim3(1024), dim3(256), 0, stream, qkv, out);
  }
}

// Round 14
// 55.027 us; speedup vs baseline: 1.2553x; 1.0612x over previous
//
#include <hip/hip_runtime.h>
#include <hip/hip_bf16.h>

typedef __attribute__((ext_vector_type(4))) float f32x4;
typedef __attribute__((ext_vector_type(16))) float f32x16;
typedef __attribute__((ext_vector_type(4))) float f4;
typedef __attribute__((ext_vector_type(8))) short bf16x8;
typedef __attribute__((ext_vector_type(4))) short s16x4;
typedef __attribute__((ext_vector_type(4))) unsigned u32x4;

#define T_LEN 2048
#define SPAD 72
// log2(e)/64: folds BOTH 1/8 scale factors and the exp->exp2 conversion.
#define QSCALE 0.022542110013890054f

// LDS slot swizzle: mixes row bits 0-2 and 3-5 -> any lane group (stride
// 1/4/8) hits 8 distinct 16B slots. Verified: bank conflicts = 0 (round 11).
#define SWZ(r) (((r) ^ ((r) >> 3)) & 7)

__device__ inline short f2bf(float f) {
  unsigned u = __builtin_bit_cast(unsigned, f);
  return (short)((u + 0x7fffu + ((u >> 16) & 1u)) >> 16);
}

// ---------------------------------------------------------------------------
// prep: single-launch K-transpose + V-tile (Q prep dropped: attn loads Q
// directly from fp32 qkv). grid = 5120, block = 256.
//   bid < 1024 : K -> [head][stile][row][c ^ (SWZ(row)<<3)]
//   bid >= 1024: V -> [head][stile][c][s ^ (SWZ(c)<<3)]
// ---------------------------------------------------------------------------
__global__ __launch_bounds__(256) void prep(const float* __restrict__ qkv,
                                            short* __restrict__ kt,
                                            short* __restrict__ vb) {
  __shared__ float tile[64][65];
  const int bid = blockIdx.x;
  const int tid = threadIdx.x;

  if (bid < 1024) {  // ---- K transpose ----
    const int tch = bid & 31;
    const int head = bid >> 5;
    const int b = head >> 3, h = head & 7;
    const float* src = qkv + ((size_t)b * 1536 + 512 + h * 64) * T_LEN + tch * 64;
    short* dst = kt + (size_t)head * 131072 + (size_t)tch * 4096;

    for (int e = tid; e < 4096; e += 256) {
      int c = e >> 6, t = e & 63;
      tile[c][t] = src[(size_t)c * T_LEN + t];
    }
    __syncthreads();
    for (int e = tid; e < 2048; e += 256) {
      int t = e >> 5, c2 = (e & 31) * 2;
      unsigned lo = (unsigned short)f2bf(tile[c2][t]);
      unsigned hi = (unsigned short)f2bf(tile[c2 + 1][t]);
      int cdst = c2 ^ (SWZ(t) << 3);
      *(unsigned*)&dst[t * 64 + cdst] = lo | (hi << 16);
    }
  } else {  // ---- V tiles ----
    int id = (bid - 1024) * 256 + tid;  // 0..1048575; 4 shorts each
    int s4 = id & 15;
    int c = (id >> 4) & 63;
    int stile = (id >> 10) & 31;
    int head = id >> 15;
    int b = head >> 3, h = head & 7;
    const float* src =
        qkv + ((size_t)b * 1536 + 1024 + h * 64 + c) * T_LEN + stile * 64 + s4 * 4;
    f4 s = *(const f4*)src;
    s16x4 o;
#pragma unroll
    for (int j = 0; j < 4; ++j) o[j] = f2bf(s[j]);
    size_t dsts =
        (((size_t)head * 32 + stile) * 64 + c) * 64 + ((s4 * 4) ^ (SWZ(c) << 3));
    *(s16x4*)&vb[dsts] = o;
  }
}

// ---------------------------------------------------------------------------
// attn14: attn13 (s-split 8-wave blocks, 4 waves/SIMD) +
//   (a) Q loaded directly from fp32 qkv (QSCALE+f2bf in-kernel, once/block)
//   (b) l computed on the MATRIX pipe: l_acc = mfma(ones, pf, l_acc) --
//       D[.][t] = sum_k P[k][t]; removes all psum VALU + epilogue shfl.
// grid = 512 = qblk(16) x head(32); block = 512.
// ---------------------------------------------------------------------------
__global__ __launch_bounds__(512, 4) void attn14(const float* __restrict__ qkv,
                                                 const short* __restrict__ Kt,
                                                 const short* __restrict__ Vb,
                                                 float* __restrict__ out) {
  __shared__ short KV[2][2][2][4096];  // [grp][buf][0=K,1=V][64x64 tile]

  const int bid = blockIdx.x;
  const int head = bid & 31;  // head pinned to one XCD's L2
  const int qblk = bid >> 5;  // 0..15

  const int tid = threadIdx.x;
  const int wave = tid >> 6;   // 0..7
  const int grp = wave >> 2;   // s-half
  const int wv = wave & 3;     // wave within group
  const int lane = tid & 63;
  const int l31 = lane & 31;
  const int hi = lane >> 5;

  const int t0 = qblk * 128 + wv * 32;  // this wave's 32 query rows
  const int sbase = grp * 16;           // this group's first s-tile

  const int b = head >> 3, h = head & 7;
  const float* Qf = qkv + ((size_t)b * 1536 + h * 64) * T_LEN;
  const short* Kh = Kt + (size_t)head * 131072;
  const short* Vh = Vb + (size_t)head * 131072;
  float* O = out + (size_t)head * 131072;

  const int sw0 = SWZ(l31) << 3;
  const int sw1 = SWZ(l31 + 32) << 3;

  auto stage = [&](int buf, int it) {  // it = tile within group (0..15)
#pragma unroll
    for (int j = 0; j < 4; ++j) {
      const int chunk = wv * 4 + j;  // 0-7 = K, 8-15 = V
      const short* g =
          (chunk < 8 ? Kh : Vh) + (sbase + it) * 4096 + (chunk & 7) * 512 + lane * 8;
      short* l = &KV[grp][buf][chunk >> 3][(chunk & 7) * 512];
      __builtin_amdgcn_global_load_lds((const __attribute__((address_space(1))) void*)g,
                                       (__attribute__((address_space(3))) void*)l,
                                       16, 0, 0);
    }
  };

  stage(0, 0);  // issue first tile before Q conversion (hides Q load latency)

  // Q (B operand) direct from fp32: lane holds B[k=c=ck*16+hi*8+j][col=t=l31]
  bf16x8 aq[4];
#pragma unroll
  for (int ck = 0; ck < 4; ++ck) {
    float qv[8];
#pragma unroll
    for (int j = 0; j < 8; ++j)
      qv[j] = Qf[(size_t)(ck * 16 + hi * 8 + j) * T_LEN + t0 + l31];
#pragma unroll
    for (int j = 0; j < 8; ++j) aq[ck][j] = f2bf(qv[j] * QSCALE);
  }

  // ones A-fragment for the l-MFMA (bf16 1.0 = 0x3F80)
  bf16x8 ones;
#pragma unroll
  for (int j = 0; j < 8; ++j) ones[j] = (short)0x3F80;

  f32x16 l_acc;
  f32x16 o_acc[2];
#pragma unroll
  for (int j = 0; j < 16; ++j) { o_acc[0][j] = 0.f; o_acc[1][j] = 0.f; l_acc[j] = 0.f; }

  auto tile_body = [&](int buf) {
    f32x16 s0, s1;
#pragma unroll
    for (int j = 0; j < 16; ++j) { s0[j] = 0.f; s1[j] = 0.f; }
    __builtin_amdgcn_s_setprio(1);
#pragma unroll
    for (int ck = 0; ck < 4; ++ck) {
      const bf16x8 k0 = *(const bf16x8*)&KV[grp][buf][0][l31 * 64 + ((ck * 16 + hi * 8) ^ sw0)];
      s0 = __builtin_amdgcn_mfma_f32_32x32x16_bf16(k0, aq[ck], s0, 0, 0, 0);
      const bf16x8 k1 = *(const bf16x8*)&KV[grp][buf][0][(32 + l31) * 64 + ((ck * 16 + hi * 8) ^ sw1)];
      s1 = __builtin_amdgcn_mfma_f32_32x32x16_bf16(k1, aq[ck], s1, 0, 0, 0);
    }
    __builtin_amdgcn_s_setprio(0);

    bf16x8 pf[4];
    const f32x16* sv[2] = {&s0, &s1};
#pragma unroll
    for (int sbk = 0; sbk < 2; ++sbk) {
      float p[16];
#pragma unroll
      for (int j = 0; j < 16; ++j) p[j] = __builtin_amdgcn_exp2f((*sv[sbk])[j]);
      unsigned w0, w1, w2, w3, w4, w5, w6, w7;
      asm("v_cvt_pk_bf16_f32 %0, %1, %2" : "=v"(w0) : "v"(p[0]), "v"(p[1]));
      asm("v_cvt_pk_bf16_f32 %0, %1, %2" : "=v"(w1) : "v"(p[2]), "v"(p[3]));
      asm("v_cvt_pk_bf16_f32 %0, %1, %2" : "=v"(w2) : "v"(p[4]), "v"(p[5]));
      asm("v_cvt_pk_bf16_f32 %0, %1, %2" : "=v"(w3) : "v"(p[6]), "v"(p[7]));
      asm("v_cvt_pk_bf16_f32 %0, %1, %2" : "=v"(w4) : "v"(p[8]), "v"(p[9]));
      asm("v_cvt_pk_bf16_f32 %0, %1, %2" : "=v"(w5) : "v"(p[10]), "v"(p[11]));
      asm("v_cvt_pk_bf16_f32 %0, %1, %2" : "=v"(w6) : "v"(p[12]), "v"(p[13]));
      asm("v_cvt_pk_bf16_f32 %0, %1, %2" : "=v"(w7) : "v"(p[14]), "v"(p[15]));
      // vdst.high <-> vsrc.low; vdst = low-s word: one swap fills two words
      asm("v_permlane32_swap_b32 %0, %1" : "+v"(w0), "+v"(w2));
      asm("v_permlane32_swap_b32 %0, %1" : "+v"(w1), "+v"(w3));
      asm("v_permlane32_swap_b32 %0, %1" : "+v"(w4), "+v"(w6));
      asm("v_permlane32_swap_b32 %0, %1" : "+v"(w5), "+v"(w7));
      u32x4 fe = {w0, w1, w2, w3};
      u32x4 fo = {w4, w5, w6, w7};
      pf[sbk * 2] = __builtin_bit_cast(bf16x8, fe);
      pf[sbk * 2 + 1] = __builtin_bit_cast(bf16x8, fo);
    }

    __builtin_amdgcn_s_setprio(1);
#pragma unroll
    for (int sc = 0; sc < 4; ++sc) {
      const bf16x8 v0 = *(const bf16x8*)&KV[grp][buf][1][l31 * 64 + ((sc * 16 + hi * 8) ^ sw0)];
      o_acc[0] = __builtin_amdgcn_mfma_f32_32x32x16_bf16(v0, pf[sc], o_acc[0], 0, 0, 0);
      const bf16x8 v1 = *(const bf16x8*)&KV[grp][buf][1][(32 + l31) * 64 + ((sc * 16 + hi * 8) ^ sw1)];
      o_acc[1] = __builtin_amdgcn_mfma_f32_32x32x16_bf16(v1, pf[sc], o_acc[1], 0, 0, 0);
      l_acc = __builtin_amdgcn_mfma_f32_32x32x16_bf16(ones, pf[sc], l_acc, 0, 0, 0);
    }
    __builtin_amdgcn_s_setprio(0);
  };

  __syncthreads();  // tile 0 staged (vmcnt drained by barrier semantics)

  // 16 tiles per group, unroll-by-2 (buf compile-time constant)
  for (int itp = 0; itp < 8; ++itp) {
    const int it = itp * 2;
    stage(1, it + 1);                  // prefetch under compute(buf0)
    tile_body(0);
    __syncthreads();
    if (itp < 7) stage(0, it + 2);
    tile_body(1);
    __syncthreads();
  }

  // ---- combine: cross-group add via LDS (l_acc[0] = this group's l(t)) ----
  const float lg = l_acc[0];
  float* xb = (float*)&KV[0][0][0][0];  // 64 KB scratch; stride 33 -> no conflicts
  if (grp == 1) {
    float* dst = xb + (wv * 64 + lane) * 33;
#pragma unroll
    for (int j = 0; j < 16; ++j) { dst[j] = o_acc[0][j]; dst[16 + j] = o_acc[1][j]; }
    dst[32] = lg;
  }
  __syncthreads();
  if (grp == 0) {
    const float* src = xb + (wv * 64 + lane) * 33;
    const float rl = 1.0f / (lg + src[32]);
#pragma unroll
    for (int j = 0; j < 16; ++j) {
      const int c0 = (j & 3) + 8 * (j >> 2) + 4 * hi;
      O[(size_t)c0 * T_LEN + t0 + l31] = (o_acc[0][j] + src[j]) * rl;
      O[(size_t)(32 + c0) * T_LEN + t0 + l31] = (o_acc[1][j] + src[16 + j]) * rl;
    }
  }
}

// ---------------------------------------------------------------------------
// Fallback (round-1 kernel) if ws_size is too small for the bf16 prep buffers.
// ---------------------------------------------------------------------------
__global__ __launch_bounds__(256) void attn_fwd(const float* __restrict__ qkv,
                                                float* __restrict__ out) {
  __shared__ short KtS[64][SPAD];
  __shared__ short VtS[64][SPAD];
  __shared__ short PbS[4][16][SPAD];

  const int bid = blockIdx.x;
  const int qt = bid & 31;
  const int head = bid >> 5;
  const int b = head >> 3, h = head & 7;

  const size_t base = ((size_t)b * 1536 + h * 64) * T_LEN;
  const float* Q = qkv + base;
  const float* K = qkv + base + (size_t)512 * T_LEN;
  const float* V = qkv + base + (size_t)1024 * T_LEN;
  float* O = out + ((size_t)b * 512 + h * 64) * T_LEN;

  const int tid = threadIdx.x;
  const int wave = tid >> 6;
  const int lane = tid & 63;
  const int l15 = lane & 15;
  const int l4 = lane >> 4;
  const int t0 = qt * 64 + wave * 16;

  bf16x8 aq[2];
#pragma unroll
  for (int kk = 0; kk < 2; ++kk)
#pragma unroll
    for (int j = 0; j < 8; ++j) {
      int c = kk * 32 + l4 * 8 + j;
      aq[kk][j] = f2bf(Q[(size_t)c * T_LEN + t0 + l15]);
    }

  float m_run[4], l_run[4];
  f32x4 o_acc[4];
#pragma unroll
  for (int r = 0; r < 4; ++r) { m_run[r] = -1e30f; l_run[r] = 0.f; }
#pragma unroll
  for (int n = 0; n < 4; ++n) o_acc[n] = (f32x4){0.f, 0.f, 0.f, 0.f};

  const float inv64 = 0.015625f;

  for (int s0 = 0; s0 < T_LEN; s0 += 64) {
    __syncthreads();
    for (int e = tid; e < 4096; e += 256) {
      int c = e >> 6, s = e & 63;
      KtS[s][c] = f2bf(K[(size_t)c * T_LEN + s0 + s]);
      VtS[c][s] = f2bf(V[(size_t)c * T_LEN + s0 + s]);
    }
    __syncthreads();

    f32x4 sacc[4];
#pragma unroll
    for (int n = 0; n < 4; ++n) {
      const bf16x8 bk0 = *(const bf16x8*)&KtS[16 * n + l15][l4 * 8];
      const bf16x8 bk1 = *(const bf16x8*)&KtS[16 * n + l15][32 + l4 * 8];
      f32x4 z = (f32x4){0.f, 0.f, 0.f, 0.f};
      z = __builtin_amdgcn_mfma_f32_16x16x32_bf16(aq[0], bk0, z, 0, 0, 0);
      z = __builtin_amdgcn_mfma_f32_16x16x32_bf16(aq[1], bk1, z, 0, 0, 0);
      sacc[n] = z;
    }

#pragma unroll
    for (int r = 0; r < 4; ++r) {
      float mx = fmaxf(fmaxf(sacc[0][r], sacc[1][r]),
                       fmaxf(sacc[2][r], sacc[3][r])) * inv64;
#pragma unroll
      for (int off = 8; off >= 1; off >>= 1)
        mx = fmaxf(mx, __shfl_xor(mx, off, 64));
      const float m_new = fmaxf(m_run[r], mx);
      const float alpha = __expf(m_run[r] - m_new);
      float psum = 0.f;
#pragma unroll
      for (int n = 0; n < 4; ++n) {
        float p = __expf(sacc[n][r] * inv64 - m_new);
        psum += p;
        PbS[wave][l4 * 4 + r][16 * n + l15] = f2bf(p);
      }
#pragma unroll
      for (int off = 8; off >= 1; off >>= 1)
        psum += __shfl_xor(psum, off, 64);
      l_run[r] = l_run[r] * alpha + psum;
      m_run[r] = m_new;
#pragma unroll
      for (int n = 0; n < 4; ++n) o_acc[n][r] *= alpha;
    }

    const bf16x8 ap0 = *(const bf16x8*)&PbS[wave][l15][l4 * 8];
    const bf16x8 ap1 = *(const bf16x8*)&PbS[wave][l15][32 + l4 * 8];
#pragma unroll
    for (int n = 0; n < 4; ++n) {
      const bf16x8 bv0 = *(const bf16x8*)&VtS[16 * n + l15][l4 * 8];
      const bf16x8 bv1 = *(const bf16x8*)&VtS[16 * n + l15][32 + l4 * 8];
      o_acc[n] = __builtin_amdgcn_mfma_f32_16x16x32_bf16(ap0, bv0, o_acc[n], 0, 0, 0);
      o_acc[n] = __builtin_amdgcn_mfma_f32_16x16x32_bf16(ap1, bv1, o_acc[n], 0, 0, 0);
    }
  }

#pragma unroll
  for (int n = 0; n < 4; ++n)
#pragma unroll
    for (int r = 0; r < 4; ++r) {
      const int c = 16 * n + l15;
      const int t = t0 + l4 * 4 + r;
      O[(size_t)c * T_LEN + t] = o_acc[n][r] / l_run[r];
    }
}

extern "C" void kernel_launch(void* const* d_in, const int* in_sizes, int n_in,
                              void* d_out, int out_size, void* d_ws, size_t ws_size,
                              hipStream_t stream) {
  const float* qkv = (const float*)d_in[0];
  float* out = (float*)d_out;
  const size_t per_buf = (size_t)32 * T_LEN * 64;        // shorts per K/V buffer
  const size_t need = per_buf * 2 * sizeof(short);       // 16.8 MB
  if (ws_size >= need) {
    short* kt = (short*)d_ws;
    short* vb = kt + per_buf;
    hipLaunchKernelGGL(prep, dim3(5120), dim3(256), 0, stream, qkv, kt, vb);
    hipLaunchKernelGGL(attn14, dim3(512), dim3(512), 0, stream, qkv, kt, vb, out);
  } else {
    hipLaunchKernelGGL(attn_fwd, dim3(1024), dim3(256), 0, stream, qkv, out);
  }
}

// Round 15
// 53.745 us; speedup vs baseline: 1.2853x; 1.0239x over previous
//
#include <hip/hip_runtime.h>
#include <hip/hip_bf16.h>

typedef __attribute__((ext_vector_type(4))) float f32x4;
typedef __attribute__((ext_vector_type(16))) float f32x16;
typedef __attribute__((ext_vector_type(4))) float f4;
typedef __attribute__((ext_vector_type(8))) short bf16x8;
typedef __attribute__((ext_vector_type(4))) short s16x4;
typedef __attribute__((ext_vector_type(4))) unsigned u32x4;

#define T_LEN 2048
#define SPAD 72
// log2(e)/64: folds BOTH 1/8 scale factors and the exp->exp2 conversion.
#define QSCALE 0.022542110013890054f

// LDS slot swizzle: mixes row bits 0-2 and 3-5 -> any lane group (stride
// 1/4/8) hits 8 distinct 16B slots. Verified: bank conflicts = 0 (round 11).
#define SWZ(r) (((r) ^ ((r) >> 3)) & 7)

__device__ inline short f2bf(float f) {
  unsigned u = __builtin_bit_cast(unsigned, f);
  return (short)((u + 0x7fffu + ((u >> 16) & 1u)) >> 16);
}

// ---------------------------------------------------------------------------
// prep: single-launch K-transpose + V-tile (Q prep dropped: attn loads Q
// directly from fp32 qkv). grid = 5120, block = 256.
//   bid < 1024 : K -> [head][stile][row][c ^ (SWZ(row)<<3)]
//   bid >= 1024: V -> [head][stile][c][s ^ (SWZ(c)<<3)]
// ---------------------------------------------------------------------------
__global__ __launch_bounds__(256) void prep(const float* __restrict__ qkv,
                                            short* __restrict__ kt,
                                            short* __restrict__ vb) {
  __shared__ float tile[64][65];
  const int bid = blockIdx.x;
  const int tid = threadIdx.x;

  if (bid < 1024) {  // ---- K transpose ----
    const int tch = bid & 31;
    const int head = bid >> 5;
    const int b = head >> 3, h = head & 7;
    const float* src = qkv + ((size_t)b * 1536 + 512 + h * 64) * T_LEN + tch * 64;
    short* dst = kt + (size_t)head * 131072 + (size_t)tch * 4096;

    for (int e = tid; e < 4096; e += 256) {
      int c = e >> 6, t = e & 63;
      tile[c][t] = src[(size_t)c * T_LEN + t];
    }
    __syncthreads();
    for (int e = tid; e < 2048; e += 256) {
      int t = e >> 5, c2 = (e & 31) * 2;
      unsigned lo = (unsigned short)f2bf(tile[c2][t]);
      unsigned hi = (unsigned short)f2bf(tile[c2 + 1][t]);
      int cdst = c2 ^ (SWZ(t) << 3);
      *(unsigned*)&dst[t * 64 + cdst] = lo | (hi << 16);
    }
  } else {  // ---- V tiles ----
    int id = (bid - 1024) * 256 + tid;  // 0..1048575; 4 shorts each
    int s4 = id & 15;
    int c = (id >> 4) & 63;
    int stile = (id >> 10) & 31;
    int head = id >> 15;
    int b = head >> 3, h = head & 7;
    const float* src =
        qkv + ((size_t)b * 1536 + 1024 + h * 64 + c) * T_LEN + stile * 64 + s4 * 4;
    f4 s = *(const f4*)src;
    s16x4 o;
#pragma unroll
    for (int j = 0; j < 4; ++j) o[j] = f2bf(s[j]);
    size_t dsts =
        (((size_t)head * 32 + stile) * 64 + c) * 64 + ((s4 * 4) ^ (SWZ(c) << 3));
    *(s16x4*)&vb[dsts] = o;
  }
}

// ---------------------------------------------------------------------------
// attn15: attn13 compute body (psum on VALU -- round 14's l-MFMA reverted:
// it added 128 cyc/wave-tile on the critical matrix pipe to save ~72 VALU
// cyc on a non-binding pipe) + round 14's prep wins (Q direct from fp32,
// merged single prep launch). s-split 8-wave blocks, 4 waves/SIMD.
// grid = 512 = qblk(16) x head(32); block = 512.
// ---------------------------------------------------------------------------
__global__ __launch_bounds__(512, 4) void attn15(const float* __restrict__ qkv,
                                                 const short* __restrict__ Kt,
                                                 const short* __restrict__ Vb,
                                                 float* __restrict__ out) {
  __shared__ short KV[2][2][2][4096];  // [grp][buf][0=K,1=V][64x64 tile]

  const int bid = blockIdx.x;
  const int head = bid & 31;  // head pinned to one XCD's L2
  const int qblk = bid >> 5;  // 0..15

  const int tid = threadIdx.x;
  const int wave = tid >> 6;   // 0..7
  const int grp = wave >> 2;   // s-half
  const int wv = wave & 3;     // wave within group
  const int lane = tid & 63;
  const int l31 = lane & 31;
  const int hi = lane >> 5;

  const int t0 = qblk * 128 + wv * 32;  // this wave's 32 query rows
  const int sbase = grp * 16;           // this group's first s-tile

  const int b = head >> 3, h = head & 7;
  const float* Qf = qkv + ((size_t)b * 1536 + h * 64) * T_LEN;
  const short* Kh = Kt + (size_t)head * 131072;
  const short* Vh = Vb + (size_t)head * 131072;
  float* O = out + (size_t)head * 131072;

  const int sw0 = SWZ(l31) << 3;
  const int sw1 = SWZ(l31 + 32) << 3;

  auto stage = [&](int buf, int it) {  // it = tile within group (0..15)
#pragma unroll
    for (int j = 0; j < 4; ++j) {
      const int chunk = wv * 4 + j;  // 0-7 = K, 8-15 = V
      const short* g =
          (chunk < 8 ? Kh : Vh) + (sbase + it) * 4096 + (chunk & 7) * 512 + lane * 8;
      short* l = &KV[grp][buf][chunk >> 3][(chunk & 7) * 512];
      __builtin_amdgcn_global_load_lds((const __attribute__((address_space(1))) void*)g,
                                       (__attribute__((address_space(3))) void*)l,
                                       16, 0, 0);
    }
  };

  stage(0, 0);  // issue first tile before Q conversion (hides Q load latency)

  // Q (B operand) direct from fp32: lane holds B[k=c=ck*16+hi*8+j][col=t=l31]
  bf16x8 aq[4];
#pragma unroll
  for (int ck = 0; ck < 4; ++ck) {
    float qv[8];
#pragma unroll
    for (int j = 0; j < 8; ++j)
      qv[j] = Qf[(size_t)(ck * 16 + hi * 8 + j) * T_LEN + t0 + l31];
#pragma unroll
    for (int j = 0; j < 8; ++j) aq[ck][j] = f2bf(qv[j] * QSCALE);
  }

  float l_lane = 0.f;
  f32x16 o_acc[2];
#pragma unroll
  for (int j = 0; j < 16; ++j) { o_acc[0][j] = 0.f; o_acc[1][j] = 0.f; }

  auto tile_body = [&](int buf) {
    f32x16 s0, s1;
#pragma unroll
    for (int j = 0; j < 16; ++j) { s0[j] = 0.f; s1[j] = 0.f; }
    __builtin_amdgcn_s_setprio(1);
#pragma unroll
    for (int ck = 0; ck < 4; ++ck) {
      const bf16x8 k0 = *(const bf16x8*)&KV[grp][buf][0][l31 * 64 + ((ck * 16 + hi * 8) ^ sw0)];
      s0 = __builtin_amdgcn_mfma_f32_32x32x16_bf16(k0, aq[ck], s0, 0, 0, 0);
      const bf16x8 k1 = *(const bf16x8*)&KV[grp][buf][0][(32 + l31) * 64 + ((ck * 16 + hi * 8) ^ sw1)];
      s1 = __builtin_amdgcn_mfma_f32_32x32x16_bf16(k1, aq[ck], s1, 0, 0, 0);
    }
    __builtin_amdgcn_s_setprio(0);

    float ps0 = 0.f, ps1 = 0.f, ps2 = 0.f, ps3 = 0.f;
    bf16x8 pf[4];
    const f32x16* sv[2] = {&s0, &s1};
#pragma unroll
    for (int sbk = 0; sbk < 2; ++sbk) {
      float p[16];
#pragma unroll
      for (int j = 0; j < 16; ++j) p[j] = __builtin_amdgcn_exp2f((*sv[sbk])[j]);
      ps0 += p[0] + p[4] + p[8] + p[12];
      ps1 += p[1] + p[5] + p[9] + p[13];
      ps2 += p[2] + p[6] + p[10] + p[14];
      ps3 += p[3] + p[7] + p[11] + p[15];
      unsigned w0, w1, w2, w3, w4, w5, w6, w7;
      asm("v_cvt_pk_bf16_f32 %0, %1, %2" : "=v"(w0) : "v"(p[0]), "v"(p[1]));
      asm("v_cvt_pk_bf16_f32 %0, %1, %2" : "=v"(w1) : "v"(p[2]), "v"(p[3]));
      asm("v_cvt_pk_bf16_f32 %0, %1, %2" : "=v"(w2) : "v"(p[4]), "v"(p[5]));
      asm("v_cvt_pk_bf16_f32 %0, %1, %2" : "=v"(w3) : "v"(p[6]), "v"(p[7]));
      asm("v_cvt_pk_bf16_f32 %0, %1, %2" : "=v"(w4) : "v"(p[8]), "v"(p[9]));
      asm("v_cvt_pk_bf16_f32 %0, %1, %2" : "=v"(w5) : "v"(p[10]), "v"(p[11]));
      asm("v_cvt_pk_bf16_f32 %0, %1, %2" : "=v"(w6) : "v"(p[12]), "v"(p[13]));
      asm("v_cvt_pk_bf16_f32 %0, %1, %2" : "=v"(w7) : "v"(p[14]), "v"(p[15]));
      // vdst.high <-> vsrc.low; vdst = low-s word: one swap fills two words
      asm("v_permlane32_swap_b32 %0, %1" : "+v"(w0), "+v"(w2));
      asm("v_permlane32_swap_b32 %0, %1" : "+v"(w1), "+v"(w3));
      asm("v_permlane32_swap_b32 %0, %1" : "+v"(w4), "+v"(w6));
      asm("v_permlane32_swap_b32 %0, %1" : "+v"(w5), "+v"(w7));
      u32x4 fe = {w0, w1, w2, w3};
      u32x4 fo = {w4, w5, w6, w7};
      pf[sbk * 2] = __builtin_bit_cast(bf16x8, fe);
      pf[sbk * 2 + 1] = __builtin_bit_cast(bf16x8, fo);
    }
    l_lane += (ps0 + ps1) + (ps2 + ps3);

    __builtin_amdgcn_s_setprio(1);
#pragma unroll
    for (int sc = 0; sc < 4; ++sc) {
      const bf16x8 v0 = *(const bf16x8*)&KV[grp][buf][1][l31 * 64 + ((sc * 16 + hi * 8) ^ sw0)];
      o_acc[0] = __builtin_amdgcn_mfma_f32_32x32x16_bf16(v0, pf[sc], o_acc[0], 0, 0, 0);
      const bf16x8 v1 = *(const bf16x8*)&KV[grp][buf][1][(32 + l31) * 64 + ((sc * 16 + hi * 8) ^ sw1)];
      o_acc[1] = __builtin_amdgcn_mfma_f32_32x32x16_bf16(v1, pf[sc], o_acc[1], 0, 0, 0);
    }
    __builtin_amdgcn_s_setprio(0);
  };

  __syncthreads();  // tile 0 staged (vmcnt drained by barrier semantics)

  // 16 tiles per group, unroll-by-2 (buf compile-time constant)
  for (int itp = 0; itp < 8; ++itp) {
    const int it = itp * 2;
    stage(1, it + 1);                  // prefetch under compute(buf0)
    tile_body(0);
    __syncthreads();
    if (itp < 7) stage(0, it + 2);
    tile_body(1);
    __syncthreads();
  }

  // ---- combine: group-local l per row, then cross-group add via LDS ----
  const float lg = l_lane + __shfl_xor(l_lane, 32, 64);
  float* xb = (float*)&KV[0][0][0][0];  // 64 KB scratch; stride 33 -> no conflicts
  if (grp == 1) {
    float* dst = xb + (wv * 64 + lane) * 33;
#pragma unroll
    for (int j = 0; j < 16; ++j) { dst[j] = o_acc[0][j]; dst[16 + j] = o_acc[1][j]; }
    dst[32] = lg;
  }
  __syncthreads();
  if (grp == 0) {
    const float* src = xb + (wv * 64 + lane) * 33;
    const float rl = 1.0f / (lg + src[32]);
#pragma unroll
    for (int j = 0; j < 16; ++j) {
      const int c0 = (j & 3) + 8 * (j >> 2) + 4 * hi;
      O[(size_t)c0 * T_LEN + t0 + l31] = (o_acc[0][j] + src[j]) * rl;
      O[(size_t)(32 + c0) * T_LEN + t0 + l31] = (o_acc[1][j] + src[16 + j]) * rl;
    }
  }
}

// ---------------------------------------------------------------------------
// Fallback (round-1 kernel) if ws_size is too small for the bf16 prep buffers.
// ---------------------------------------------------------------------------
__global__ __launch_bounds__(256) void attn_fwd(const float* __restrict__ qkv,
                                                float* __restrict__ out) {
  __shared__ short KtS[64][SPAD];
  __shared__ short VtS[64][SPAD];
  __shared__ short PbS[4][16][SPAD];

  const int bid = blockIdx.x;
  const int qt = bid & 31;
  const int head = bid >> 5;
  const int b = head >> 3, h = head & 7;

  const size_t base = ((size_t)b * 1536 + h * 64) * T_LEN;
  const float* Q = qkv + base;
  const float* K = qkv + base + (size_t)512 * T_LEN;
  const float* V = qkv + base + (size_t)1024 * T_LEN;
  float* O = out + ((size_t)b * 512 + h * 64) * T_LEN;

  const int tid = threadIdx.x;
  const int wave = tid >> 6;
  const int lane = tid & 63;
  const int l15 = lane & 15;
  const int l4 = lane >> 4;
  const int t0 = qt * 64 + wave * 16;

  bf16x8 aq[2];
#pragma unroll
  for (int kk = 0; kk < 2; ++kk)
#pragma unroll
    for (int j = 0; j < 8; ++j) {
      int c = kk * 32 + l4 * 8 + j;
      aq[kk][j] = f2bf(Q[(size_t)c * T_LEN + t0 + l15]);
    }

  float m_run[4], l_run[4];
  f32x4 o_acc[4];
#pragma unroll
  for (int r = 0; r < 4; ++r) { m_run[r] = -1e30f; l_run[r] = 0.f; }
#pragma unroll
  for (int n = 0; n < 4; ++n) o_acc[n] = (f32x4){0.f, 0.f, 0.f, 0.f};

  const float inv64 = 0.015625f;

  for (int s0 = 0; s0 < T_LEN; s0 += 64) {
    __syncthreads();
    for (int e = tid; e < 4096; e += 256) {
      int c = e >> 6, s = e & 63;
      KtS[s][c] = f2bf(K[(size_t)c * T_LEN + s0 + s]);
      VtS[c][s] = f2bf(V[(size_t)c * T_LEN + s0 + s]);
    }
    __syncthreads();

    f32x4 sacc[4];
#pragma unroll
    for (int n = 0; n < 4; ++n) {
      const bf16x8 bk0 = *(const bf16x8*)&KtS[16 * n + l15][l4 * 8];
      const bf16x8 bk1 = *(const bf16x8*)&KtS[16 * n + l15][32 + l4 * 8];
      f32x4 z = (f32x4){0.f, 0.f, 0.f, 0.f};
      z = __builtin_amdgcn_mfma_f32_16x16x32_bf16(aq[0], bk0, z, 0, 0, 0);
      z = __builtin_amdgcn_mfma_f32_16x16x32_bf16(aq[1], bk1, z, 0, 0, 0);
      sacc[n] = z;
    }

#pragma unroll
    for (int r = 0; r < 4; ++r) {
      float mx = fmaxf(fmaxf(sacc[0][r], sacc[1][r]),
                       fmaxf(sacc[2][r], sacc[3][r])) * inv64;
#pragma unroll
      for (int off = 8; off >= 1; off >>= 1)
        mx = fmaxf(mx, __shfl_xor(mx, off, 64));
      const float m_new = fmaxf(m_run[r], mx);
      const float alpha = __expf(m_run[r] - m_new);
      float psum = 0.f;
#pragma unroll
      for (int n = 0; n < 4; ++n) {
        float p = __expf(sacc[n][r] * inv64 - m_new);
        psum += p;
        PbS[wave][l4 * 4 + r][16 * n + l15] = f2bf(p);
      }
#pragma unroll
      for (int off = 8; off >= 1; off >>= 1)
        psum += __shfl_xor(psum, off, 64);
      l_run[r] = l_run[r] * alpha + psum;
      m_run[r] = m_new;
#pragma unroll
      for (int n = 0; n < 4; ++n) o_acc[n][r] *= alpha;
    }

    const bf16x8 ap0 = *(const bf16x8*)&PbS[wave][l15][l4 * 8];
    const bf16x8 ap1 = *(const bf16x8*)&PbS[wave][l15][32 + l4 * 8];
#pragma unroll
    for (int n = 0; n < 4; ++n) {
      const bf16x8 bv0 = *(const bf16x8*)&VtS[16 * n + l15][l4 * 8];
      const bf16x8 bv1 = *(const bf16x8*)&VtS[16 * n + l15][32 + l4 * 8];
      o_acc[n] = __builtin_amdgcn_mfma_f32_16x16x32_bf16(ap0, bv0, o_acc[n], 0, 0, 0);
      o_acc[n] = __builtin_amdgcn_mfma_f32_16x16x32_bf16(ap1, bv1, o_acc[n], 0, 0, 0);
    }
  }

#pragma unroll
  for (int n = 0; n < 4; ++n)
#pragma unroll
    for (int r = 0; r < 4; ++r) {
      const int c = 16 * n + l15;
      const int t = t0 + l4 * 4 + r;
      O[(size_t)c * T_LEN + t] = o_acc[n][r] / l_run[r];
    }
}

extern "C" void kernel_launch(void* const* d_in, const int* in_sizes, int n_in,
                              void* d_out, int out_size, void* d_ws, size_t ws_size,
                              hipStream_t stream) {
  const float* qkv = (const float*)d_in[0];
  float* out = (float*)d_out;
  const size_t per_buf = (size_t)32 * T_LEN * 64;        // shorts per K/V buffer
  const size_t need = per_buf * 2 * sizeof(short);       // 16.8 MB
  if (ws_size >= need) {
    short* kt = (short*)d_ws;
    short* vb = kt + per_buf;
    hipLaunchKernelGGL(prep, dim3(5120), dim3(256), 0, stream, qkv, kt, vb);
    hipLaunchKernelGGL(attn15, dim3(512), dim3(512), 0, stream, qkv, kt, vb, out);
  } else {
    hipLaunchKernelGGL(attn_fwd, dim3(1024), dim3(256), 0, stream, qkv, out);
  }
}

// Round 16
// 53.034 us; speedup vs baseline: 1.3025x; 1.0134x over previous
//
#include <hip/hip_runtime.h>
#include <hip/hip_bf16.h>

typedef __attribute__((ext_vector_type(4))) float f32x4;
typedef __attribute__((ext_vector_type(16))) float f32x16;
typedef __attribute__((ext_vector_type(4))) float f4;
typedef __attribute__((ext_vector_type(8))) short bf16x8;
typedef __attribute__((ext_vector_type(4))) short s16x4;
typedef __attribute__((ext_vector_type(4))) unsigned u32x4;

#define T_LEN 2048
#define SPAD 72
// log2(e)/64: folds BOTH 1/8 scale factors and the exp->exp2 conversion.
#define QSCALE 0.022542110013890054f

// LDS slot swizzle: mixes row bits 0-2 and 3-5 -> any lane group (stride
// 1/4/8) hits 8 distinct 16B slots. Verified: bank conflicts = 0 (round 11).
#define SWZ(r) (((r) ^ ((r) >> 3)) & 7)

__device__ inline short f2bf(float f) {
  unsigned u = __builtin_bit_cast(unsigned, f);
  return (short)((u + 0x7fffu + ((u >> 16) & 1u)) >> 16);
}

// ---------------------------------------------------------------------------
// prep: single-launch K-transpose + V-tile. grid = 5120, block = 256.
//   bid < 1024 : K -> [head][stile][row][c ^ (SWZ(row)<<3)]
//   bid >= 1024: V -> [head][stile][c][s ^ (SWZ(c)<<3)]
// ---------------------------------------------------------------------------
__global__ __launch_bounds__(256) void prep(const float* __restrict__ qkv,
                                            short* __restrict__ kt,
                                            short* __restrict__ vb) {
  __shared__ float tile[64][65];
  const int bid = blockIdx.x;
  const int tid = threadIdx.x;

  if (bid < 1024) {  // ---- K transpose ----
    const int tch = bid & 31;
    const int head = bid >> 5;
    const int b = head >> 3, h = head & 7;
    const float* src = qkv + ((size_t)b * 1536 + 512 + h * 64) * T_LEN + tch * 64;
    short* dst = kt + (size_t)head * 131072 + (size_t)tch * 4096;

    for (int e = tid; e < 4096; e += 256) {
      int c = e >> 6, t = e & 63;
      tile[c][t] = src[(size_t)c * T_LEN + t];
    }
    __syncthreads();
    for (int e = tid; e < 2048; e += 256) {
      int t = e >> 5, c2 = (e & 31) * 2;
      unsigned lo = (unsigned short)f2bf(tile[c2][t]);
      unsigned hi = (unsigned short)f2bf(tile[c2 + 1][t]);
      int cdst = c2 ^ (SWZ(t) << 3);
      *(unsigned*)&dst[t * 64 + cdst] = lo | (hi << 16);
    }
  } else {  // ---- V tiles ----
    int id = (bid - 1024) * 256 + tid;  // 0..1048575; 4 shorts each
    int s4 = id & 15;
    int c = (id >> 4) & 63;
    int stile = (id >> 10) & 31;
    int head = id >> 15;
    int b = head >> 3, h = head & 7;
    const float* src =
        qkv + ((size_t)b * 1536 + 1024 + h * 64 + c) * T_LEN + stile * 64 + s4 * 4;
    f4 s = *(const f4*)src;
    s16x4 o;
#pragma unroll
    for (int j = 0; j < 4; ++j) o[j] = f2bf(s[j]);
    size_t dsts =
        (((size_t)head * 32 + stile) * 64 + c) * 64 + ((s4 * 4) ^ (SWZ(c) << 3));
    *(s16x4*)&vb[dsts] = o;
  }
}

// ---------------------------------------------------------------------------
// attn16: round-15 diagnosis = wall ~= pipe SUM (no overlap); biggest
// reducible term = LDS reads. Hybrid: s-split (2 groups x 4 waves) AND
// 64 q-rows/wave (two Q-sets A/B) -> each K/V fragment ds_read feeds TWO
// MFMAs, halving LDS-read demand (20.5 -> 10.25 us/CU). Round 12's version
// failed at 1 wave/SIMD; this keeps 2/SIMD via the 8-wave block.
// grid = 256 = qblk(8) x head(32); block = 512. 1 block/CU.
// ---------------------------------------------------------------------------
__global__ __launch_bounds__(512, 2) void attn16(const float* __restrict__ qkv,
                                                 const short* __restrict__ Kt,
                                                 const short* __restrict__ Vb,
                                                 float* __restrict__ out) {
  __shared__ short KV[2][2][2][4096];  // [grp][buf][0=K,1=V][64x64 tile]

  const int bid = blockIdx.x;
  const int head = bid & 31;  // bid%8 == head%8 -> head pinned to one XCD
  const int qblk = bid >> 5;  // 0..7

  const int tid = threadIdx.x;
  const int wave = tid >> 6;   // 0..7
  const int grp = wave >> 2;   // s-half
  const int wv = wave & 3;     // wave within group
  const int lane = tid & 63;
  const int l31 = lane & 31;
  const int hi = lane >> 5;

  const int t0 = qblk * 256 + wv * 64;  // rows t0..t0+63 (sets A,B)
  const int sbase = grp * 16;           // this group's first s-tile

  const int b = head >> 3, h = head & 7;
  const float* Qf = qkv + ((size_t)b * 1536 + h * 64) * T_LEN;
  const short* Kh = Kt + (size_t)head * 131072;
  const short* Vh = Vb + (size_t)head * 131072;
  float* O = out + (size_t)head * 131072;

  const int sw0 = SWZ(l31) << 3;
  const int sw1 = SWZ(l31 + 32) << 3;

  auto stage = [&](int buf, int it) {  // it = tile within group (0..15)
#pragma unroll
    for (int j = 0; j < 4; ++j) {
      const int chunk = wv * 4 + j;  // 0-7 = K, 8-15 = V
      const short* g =
          (chunk < 8 ? Kh : Vh) + (sbase + it) * 4096 + (chunk & 7) * 512 + lane * 8;
      short* l = &KV[grp][buf][chunk >> 3][(chunk & 7) * 512];
      __builtin_amdgcn_global_load_lds((const __attribute__((address_space(1))) void*)g,
                                       (__attribute__((address_space(3))) void*)l,
                                       16, 0, 0);
    }
  };

  stage(0, 0);  // issue first tile before Q conversion (hides Q load latency)

  // Q (B operand) sets direct from fp32: lane holds B[k=c][col=t]
  bf16x8 aqA[4], aqB[4];
#pragma unroll
  for (int ck = 0; ck < 4; ++ck) {
    float qa[8], qb[8];
#pragma unroll
    for (int j = 0; j < 8; ++j) {
      qa[j] = Qf[(size_t)(ck * 16 + hi * 8 + j) * T_LEN + t0 + l31];
      qb[j] = Qf[(size_t)(ck * 16 + hi * 8 + j) * T_LEN + t0 + 32 + l31];
    }
#pragma unroll
    for (int j = 0; j < 8; ++j) {
      aqA[ck][j] = f2bf(qa[j] * QSCALE);
      aqB[ck][j] = f2bf(qb[j] * QSCALE);
    }
  }

  float lA = 0.f, lB = 0.f;
  f32x16 oA0, oA1, oB0, oB1;
#pragma unroll
  for (int j = 0; j < 16; ++j) { oA0[j] = 0.f; oA1[j] = 0.f; oB0[j] = 0.f; oB1[j] = 0.f; }

  // p = exp2(s) -> 4-partial psum -> packed PV B-frags (cvt_pk + permlane)
  auto pack = [&](const f32x16& s0, const f32x16& s1, bf16x8(&pf)[4], float& l_acc) {
    float ps0 = 0.f, ps1 = 0.f, ps2 = 0.f, ps3 = 0.f;
    const f32x16* sv[2] = {&s0, &s1};
#pragma unroll
    for (int sbk = 0; sbk < 2; ++sbk) {
      float p[16];
#pragma unroll
      for (int j = 0; j < 16; ++j) p[j] = __builtin_amdgcn_exp2f((*sv[sbk])[j]);
      ps0 += p[0] + p[4] + p[8] + p[12];
      ps1 += p[1] + p[5] + p[9] + p[13];
      ps2 += p[2] + p[6] + p[10] + p[14];
      ps3 += p[3] + p[7] + p[11] + p[15];
      unsigned w0, w1, w2, w3, w4, w5, w6, w7;
      asm("v_cvt_pk_bf16_f32 %0, %1, %2" : "=v"(w0) : "v"(p[0]), "v"(p[1]));
      asm("v_cvt_pk_bf16_f32 %0, %1, %2" : "=v"(w1) : "v"(p[2]), "v"(p[3]));
      asm("v_cvt_pk_bf16_f32 %0, %1, %2" : "=v"(w2) : "v"(p[4]), "v"(p[5]));
      asm("v_cvt_pk_bf16_f32 %0, %1, %2" : "=v"(w3) : "v"(p[6]), "v"(p[7]));
      asm("v_cvt_pk_bf16_f32 %0, %1, %2" : "=v"(w4) : "v"(p[8]), "v"(p[9]));
      asm("v_cvt_pk_bf16_f32 %0, %1, %2" : "=v"(w5) : "v"(p[10]), "v"(p[11]));
      asm("v_cvt_pk_bf16_f32 %0, %1, %2" : "=v"(w6) : "v"(p[12]), "v"(p[13]));
      asm("v_cvt_pk_bf16_f32 %0, %1, %2" : "=v"(w7) : "v"(p[14]), "v"(p[15]));
      // vdst.high <-> vsrc.low; vdst = low-s word: one swap fills two words
      asm("v_permlane32_swap_b32 %0, %1" : "+v"(w0), "+v"(w2));
      asm("v_permlane32_swap_b32 %0, %1" : "+v"(w1), "+v"(w3));
      asm("v_permlane32_swap_b32 %0, %1" : "+v"(w4), "+v"(w6));
      asm("v_permlane32_swap_b32 %0, %1" : "+v"(w5), "+v"(w7));
      u32x4 fe = {w0, w1, w2, w3};
      u32x4 fo = {w4, w5, w6, w7};
      pf[sbk * 2] = __builtin_bit_cast(bf16x8, fe);
      pf[sbk * 2 + 1] = __builtin_bit_cast(bf16x8, fo);
    }
    l_acc += (ps0 + ps1) + (ps2 + ps3);
  };

  auto tile_body = [&](int buf) {
    // ---- S^T = K Q^T for both q-sets; each K read feeds 2 MFMAs ----
    f32x16 sA0, sA1, sB0, sB1;
#pragma unroll
    for (int j = 0; j < 16; ++j) { sA0[j] = 0.f; sA1[j] = 0.f; sB0[j] = 0.f; sB1[j] = 0.f; }
    __builtin_amdgcn_s_setprio(1);
#pragma unroll
    for (int ck = 0; ck < 4; ++ck) {
      const bf16x8 k0 = *(const bf16x8*)&KV[grp][buf][0][l31 * 64 + ((ck * 16 + hi * 8) ^ sw0)];
      const bf16x8 k1 = *(const bf16x8*)&KV[grp][buf][0][(32 + l31) * 64 + ((ck * 16 + hi * 8) ^ sw1)];
      sA0 = __builtin_amdgcn_mfma_f32_32x32x16_bf16(k0, aqA[ck], sA0, 0, 0, 0);
      sA1 = __builtin_amdgcn_mfma_f32_32x32x16_bf16(k1, aqA[ck], sA1, 0, 0, 0);
      sB0 = __builtin_amdgcn_mfma_f32_32x32x16_bf16(k0, aqB[ck], sB0, 0, 0, 0);
      sB1 = __builtin_amdgcn_mfma_f32_32x32x16_bf16(k1, aqB[ck], sB1, 0, 0, 0);
    }
    __builtin_amdgcn_s_setprio(0);

    // ---- softmax + pack both sets (so V below is read once) ----
    bf16x8 pfA[4], pfB[4];
    pack(sA0, sA1, pfA, lA);
    pack(sB0, sB1, pfB, lB);

    // ---- O^T += V P^T; each V read feeds 2 MFMAs ----
    __builtin_amdgcn_s_setprio(1);
#pragma unroll
    for (int sc = 0; sc < 4; ++sc) {
      const bf16x8 v0 = *(const bf16x8*)&KV[grp][buf][1][l31 * 64 + ((sc * 16 + hi * 8) ^ sw0)];
      const bf16x8 v1 = *(const bf16x8*)&KV[grp][buf][1][(32 + l31) * 64 + ((sc * 16 + hi * 8) ^ sw1)];
      oA0 = __builtin_amdgcn_mfma_f32_32x32x16_bf16(v0, pfA[sc], oA0, 0, 0, 0);
      oA1 = __builtin_amdgcn_mfma_f32_32x32x16_bf16(v1, pfA[sc], oA1, 0, 0, 0);
      oB0 = __builtin_amdgcn_mfma_f32_32x32x16_bf16(v0, pfB[sc], oB0, 0, 0, 0);
      oB1 = __builtin_amdgcn_mfma_f32_32x32x16_bf16(v1, pfB[sc], oB1, 0, 0, 0);
    }
    __builtin_amdgcn_s_setprio(0);
  };

  __syncthreads();  // tile 0 staged (vmcnt drained by barrier semantics)

  // 16 tiles per group, unroll-by-2 (buf compile-time constant)
  for (int itp = 0; itp < 8; ++itp) {
    const int it = itp * 2;
    stage(1, it + 1);                  // prefetch under compute(buf0)
    tile_body(0);
    __syncthreads();
    if (itp < 7) stage(0, it + 2);
    tile_body(1);
    __syncthreads();
  }

  // ---- combine: two-pass cross-group add via LDS scratch (33.8KB/pass) ----
  const float lAg = lA + __shfl_xor(lA, 32, 64);
  const float lBg = lB + __shfl_xor(lB, 32, 64);
  float* xb = (float*)&KV[0][0][0][0];  // stride 33 words -> 2-way alias (free)

  // pass A (q-rows t0..t0+31)
  if (grp == 1) {
    float* dst = xb + (wv * 64 + lane) * 33;
#pragma unroll
    for (int j = 0; j < 16; ++j) { dst[j] = oA0[j]; dst[16 + j] = oA1[j]; }
    dst[32] = lAg;
  }
  __syncthreads();
  if (grp == 0) {
    const float* src = xb + (wv * 64 + lane) * 33;
    const float rl = 1.0f / (lAg + src[32]);
#pragma unroll
    for (int j = 0; j < 16; ++j) {
      const int c0 = (j & 3) + 8 * (j >> 2) + 4 * hi;
      O[(size_t)c0 * T_LEN + t0 + l31] = (oA0[j] + src[j]) * rl;
      O[(size_t)(32 + c0) * T_LEN + t0 + l31] = (oA1[j] + src[16 + j]) * rl;
    }
  }
  __syncthreads();

  // pass B (q-rows t0+32..t0+63)
  if (grp == 1) {
    float* dst = xb + (wv * 64 + lane) * 33;
#pragma unroll
    for (int j = 0; j < 16; ++j) { dst[j] = oB0[j]; dst[16 + j] = oB1[j]; }
    dst[32] = lBg;
  }
  __syncthreads();
  if (grp == 0) {
    const float* src = xb + (wv * 64 + lane) * 33;
    const float rl = 1.0f / (lBg + src[32]);
#pragma unroll
    for (int j = 0; j < 16; ++j) {
      const int c0 = (j & 3) + 8 * (j >> 2) + 4 * hi;
      O[(size_t)c0 * T_LEN + t0 + 32 + l31] = (oB0[j] + src[j]) * rl;
      O[(size_t)(32 + c0) * T_LEN + t0 + 32 + l31] = (oB1[j] + src[16 + j]) * rl;
    }
  }
}

// ---------------------------------------------------------------------------
// Fallback (round-1 kernel) if ws_size is too small for the bf16 prep buffers.
// ---------------------------------------------------------------------------
__global__ __launch_bounds__(256) void attn_fwd(const float* __restrict__ qkv,
                                                float* __restrict__ out) {
  __shared__ short KtS[64][SPAD];
  __shared__ short VtS[64][SPAD];
  __shared__ short PbS[4][16][SPAD];

  const int bid = blockIdx.x;
  const int qt = bid & 31;
  const int head = bid >> 5;
  const int b = head >> 3, h = head & 7;

  const size_t base = ((size_t)b * 1536 + h * 64) * T_LEN;
  const float* Q = qkv + base;
  const float* K = qkv + base + (size_t)512 * T_LEN;
  const float* V = qkv + base + (size_t)1024 * T_LEN;
  float* O = out + ((size_t)b * 512 + h * 64) * T_LEN;

  const int tid = threadIdx.x;
  const int wave = tid >> 6;
  const int lane = tid & 63;
  const int l15 = lane & 15;
  const int l4 = lane >> 4;
  const int t0 = qt * 64 + wave * 16;

  bf16x8 aq[2];
#pragma unroll
  for (int kk = 0; kk < 2; ++kk)
#pragma unroll
    for (int j = 0; j < 8; ++j) {
      int c = kk * 32 + l4 * 8 + j;
      aq[kk][j] = f2bf(Q[(size_t)c * T_LEN + t0 + l15]);
    }

  float m_run[4], l_run[4];
  f32x4 o_acc[4];
#pragma unroll
  for (int r = 0; r < 4; ++r) { m_run[r] = -1e30f; l_run[r] = 0.f; }
#pragma unroll
  for (int n = 0; n < 4; ++n) o_acc[n] = (f32x4){0.f, 0.f, 0.f, 0.f};

  const float inv64 = 0.015625f;

  for (int s0 = 0; s0 < T_LEN; s0 += 64) {
    __syncthreads();
    for (int e = tid; e < 4096; e += 256) {
      int c = e >> 6, s = e & 63;
      KtS[s][c] = f2bf(K[(size_t)c * T_LEN + s0 + s]);
      VtS[c][s] = f2bf(V[(size_t)c * T_LEN + s0 + s]);
    }
    __syncthreads();

    f32x4 sacc[4];
#pragma unroll
    for (int n = 0; n < 4; ++n) {
      const bf16x8 bk0 = *(const bf16x8*)&KtS[16 * n + l15][l4 * 8];
      const bf16x8 bk1 = *(const bf16x8*)&KtS[16 * n + l15][32 + l4 * 8];
      f32x4 z = (f32x4){0.f, 0.f, 0.f, 0.f};
      z = __builtin_amdgcn_mfma_f32_16x16x32_bf16(aq[0], bk0, z, 0, 0, 0);
      z = __builtin_amdgcn_mfma_f32_16x16x32_bf16(aq[1], bk1, z, 0, 0, 0);
      sacc[n] = z;
    }

#pragma unroll
    for (int r = 0; r < 4; ++r) {
      float mx = fmaxf(fmaxf(sacc[0][r], sacc[1][r]),
                       fmaxf(sacc[2][r], sacc[3][r])) * inv64;
#pragma unroll
      for (int off = 8; off >= 1; off >>= 1)
        mx = fmaxf(mx, __shfl_xor(mx, off, 64));
      const float m_new = fmaxf(m_run[r], mx);
      const float alpha = __expf(m_run[r] - m_new);
      float psum = 0.f;
#pragma unroll
      for (int n = 0; n < 4; ++n) {
        float p = __expf(sacc[n][r] * inv64 - m_new);
        psum += p;
        PbS[wave][l4 * 4 + r][16 * n + l15] = f2bf(p);
      }
#pragma unroll
      for (int off = 8; off >= 1; off >>= 1)
        psum += __shfl_xor(psum, off, 64);
      l_run[r] = l_run[r] * alpha + psum;
      m_run[r] = m_new;
#pragma unroll
      for (int n = 0; n < 4; ++n) o_acc[n][r] *= alpha;
    }

    const bf16x8 ap0 = *(const bf16x8*)&PbS[wave][l15][l4 * 8];
    const bf16x8 ap1 = *(const bf16x8*)&PbS[wave][l15][32 + l4 * 8];
#pragma unroll
    for (int n = 0; n < 4; ++n) {
      const bf16x8 bv0 = *(const bf16x8*)&VtS[16 * n + l15][l4 * 8];
      const bf16x8 bv1 = *(const bf16x8*)&VtS[16 * n + l15][32 + l4 * 8];
      o_acc[n] = __builtin_amdgcn_mfma_f32_16x16x32_bf16(ap0, bv0, o_acc[n], 0, 0, 0);
      o_acc[n] = __builtin_amdgcn_mfma_f32_16x16x32_bf16(ap1, bv1, o_acc[n], 0, 0, 0);
    }
  }

#pragma unroll
  for (int n = 0; n < 4; ++n)
#pragma unroll
    for (int r = 0; r < 4; ++r) {
      const int c = 16 * n + l15;
      const int t = t0 + l4 * 4 + r;
      O[(size_t)c * T_LEN + t] = o_acc[n][r] / l_run[r];
    }
}

extern "C" void kernel_launch(void* const* d_in, const int* in_sizes, int n_in,
                              void* d_out, int out_size, void* d_ws, size_t ws_size,
                              hipStream_t stream) {
  const float* qkv = (const float*)d_in[0];
  float* out = (float*)d_out;
  const size_t per_buf = (size_t)32 * T_LEN * 64;        // shorts per K/V buffer
  const size_t need = per_buf * 2 * sizeof(short);       // 16.8 MB
  if (ws_size >= need) {
    short* kt = (short*)d_ws;
    short* vb = kt + per_buf;
    hipLaunchKernelGGL(prep, dim3(5120), dim3(256), 0, stream, qkv, kt, vb);
    hipLaunchKernelGGL(attn16, dim3(256), dim3(512), 0, stream, qkv, kt, vb, out);
  } else {
    hipLaunchKernelGGL(attn_fwd, dim3(1024), dim3(256), 0, stream, qkv, out);
  }
}